// Round 3
// baseline (433.466 us; speedup 1.0000x reference)
//
#include <hip/hip_runtime.h>
#include <stdint.h>

#define DIMC 1536
#define LTOK 3072
#define HEADS 12
#define HD 128
#define FS 384            // H*W = 16*24
#define MAXATTN 1920
#define HTOK 1152         // first token with qf>=3 (2-chunk rows)
#define NHT 1920          // number of heavy tokens

typedef __attribute__((ext_vector_type(4))) float f32x4;
typedef __attribute__((ext_vector_type(8))) short bf16x8;

__device__ __forceinline__ unsigned short f2bf(float f) {
  union { float f; unsigned int u; } c; c.f = f;
  unsigned int u = c.u + 0x7fffu + ((c.u >> 16) & 1u);   // RNE
  return (unsigned short)(u >> 16);
}
__device__ __forceinline__ float bf2f(unsigned short s) {
  union { unsigned int u; float f; } c; c.u = (unsigned int)s << 16; return c.f;
}

// ---------------- fused fp32 -> bf16 conversion for all 5 tensors ----------------
__global__ __launch_bounds__(256)
void cvt_all_k(const float* __restrict__ x, const float* __restrict__ wq,
               const float* __restrict__ wk, const float* __restrict__ wv,
               const float* __restrict__ wo,
               unsigned short* __restrict__ xb, unsigned short* __restrict__ wqb,
               unsigned short* __restrict__ wkb, unsigned short* __restrict__ wvb,
               unsigned short* __restrict__ wob)
{
  const int i = blockIdx.x * 256 + threadIdx.x;      // uint4 index
  const int n0 = LTOK * DIMC / 4;
  const int nw = DIMC * DIMC / 4;
  const float* src; unsigned short* dst; int off;
  if (i < n0) { src = x; dst = xb; off = i; }
  else {
    int j = i - n0; int w = j / nw; off = j - w * nw;
    src = (w == 0) ? wq : (w == 1) ? wk : (w == 2) ? wv : wo;
    dst = (w == 0) ? wqb : (w == 1) ? wkb : (w == 2) ? wvb : wob;
  }
  float4 f = ((const float4*)src)[off];
  uint2 o;
  o.x = (unsigned int)f2bf(f.x) | ((unsigned int)f2bf(f.y) << 16);
  o.y = (unsigned int)f2bf(f.z) | ((unsigned int)f2bf(f.w) << 16);
  ((uint2*)dst)[off] = o;
}

// ---------------- NT GEMM: C[M,N] = A[M,K] * B[N,K]^T + bias ----------------
template <bool F32OUT>
__global__ __launch_bounds__(256)
void gemm_nt(const unsigned short* __restrict__ A,
             const unsigned short* __restrict__ B0,
             const unsigned short* __restrict__ B1,
             const unsigned short* __restrict__ B2,
             const float* __restrict__ bias0,
             const float* __restrict__ bias1,
             const float* __restrict__ bias2,
             void* __restrict__ o0, void* __restrict__ o1, void* __restrict__ o2)
{
  const int z = blockIdx.z;
  const unsigned short* Bw = (z == 0) ? B0 : (z == 1) ? B1 : B2;
  const float* bias = (z == 0) ? bias0 : (z == 1) ? bias1 : bias2;
  void* outp = (z == 0) ? o0 : (z == 1) ? o1 : o2;

  __shared__ __align__(16) unsigned short lA[128 * 32];
  __shared__ __align__(16) unsigned short lB[128 * 32];

  const int tid = threadIdx.x;
  const int wave = tid >> 6;
  const int lane = tid & 63;
  const int m0 = blockIdx.y * 128;
  const int n0 = blockIdx.x * 128;
  const int wm = (wave >> 1) * 64;
  const int wn = (wave & 1) * 64;

  f32x4 acc[4][4] = {};

  const int srow = tid >> 2;
  const int scol = (tid & 3) * 8;
  const int fr = lane & 15;
  const int fk = (lane >> 4) * 8;

  for (int k0 = 0; k0 < DIMC; k0 += 32) {
    uint4 a0 = *(const uint4*)(A  + (size_t)(m0 + srow)      * DIMC + k0 + scol);
    uint4 a1 = *(const uint4*)(A  + (size_t)(m0 + srow + 64) * DIMC + k0 + scol);
    uint4 b0 = *(const uint4*)(Bw + (size_t)(n0 + srow)      * DIMC + k0 + scol);
    uint4 b1 = *(const uint4*)(Bw + (size_t)(n0 + srow + 64) * DIMC + k0 + scol);
    *(uint4*)&lA[srow * 32 + scol]        = a0;
    *(uint4*)&lA[(srow + 64) * 32 + scol] = a1;
    *(uint4*)&lB[srow * 32 + scol]        = b0;
    *(uint4*)&lB[(srow + 64) * 32 + scol] = b1;
    __syncthreads();

    bf16x8 af[4], bf[4];
#pragma unroll
    for (int i = 0; i < 4; ++i)
      af[i] = *(const bf16x8*)&lA[(wm + i * 16 + fr) * 32 + fk];
#pragma unroll
    for (int j = 0; j < 4; ++j)
      bf[j] = *(const bf16x8*)&lB[(wn + j * 16 + fr) * 32 + fk];
#pragma unroll
    for (int i = 0; i < 4; ++i)
#pragma unroll
      for (int j = 0; j < 4; ++j)
        acc[i][j] = __builtin_amdgcn_mfma_f32_16x16x32_bf16(af[i], bf[j], acc[i][j], 0, 0, 0);
    __syncthreads();
  }

  const int col = lane & 15;
  const int rb = (lane >> 4) * 4;
#pragma unroll
  for (int j = 0; j < 4; ++j) {
    const int gn = n0 + wn + j * 16 + col;
    const float bv = bias[gn];
#pragma unroll
    for (int i = 0; i < 4; ++i) {
#pragma unroll
      for (int r = 0; r < 4; ++r) {
        const int gm = m0 + wm + i * 16 + rb + r;
        float val = acc[i][j][r] + bv;
        if (F32OUT)
          ((float*)outp)[(size_t)gm * DIMC + gn] = val;
        else
          ((unsigned short*)outp)[(size_t)gm * DIMC + gn] = f2bf(val);
      }
    }
  }
}

// ---------------- rmsnorm + 3D RoPE, in place; q additionally scaled ----------------
// q *= 1/sqrt(HD) * log2(e)  (folded so attention softmax runs in exp2 domain)
__global__ __launch_bounds__(256)
void rms_rope_k(unsigned short* __restrict__ q, unsigned short* __restrict__ k,
                const float* __restrict__ nqw, const float* __restrict__ nkw,
                const float* __restrict__ freqs)
{
  const int tok = blockIdx.x;
  const int which = blockIdx.y;
  unsigned short* row = (which ? k : q) + (size_t)tok * DIMC;
  const float* nw = which ? nkw : nqw;
  const float sc = which ? 1.f : (0.08838834764831845f * 1.4426950408889634f);
  const int tid = threadIdx.x;
  const int base = tid * 6;

  float v[6];
  float ss = 0.f;
#pragma unroll
  for (int j = 0; j < 6; ++j) {
    v[j] = bf2f(row[base + j]);
    ss += v[j] * v[j];
  }
#pragma unroll
  for (int off = 1; off < 64; off <<= 1) ss += __shfl_xor(ss, off);
  __shared__ float wsum[4];
  if ((tid & 63) == 0) wsum[tid >> 6] = ss;
  __syncthreads();
  const float total = wsum[0] + wsum[1] + wsum[2] + wsum[3];
  const float rms = rsqrtf(total * (1.f / DIMC) + 1e-6f);

  const int f = tok / FS;
  const int rem = tok - f * FS;
  const int h = rem / 24;
  const int w = rem - h * 24;

#pragma unroll
  for (int pp = 0; pp < 3; ++pp) {
    const int P = (base >> 1) + pp;
    const int p = P & 63;
    const int t = (p < 22) ? f : ((p < 43) ? h : w);
    const float fr = freqs[t * 128 + p * 2];
    const float fi = freqs[t * 128 + p * 2 + 1];
    const float e = v[2 * pp]     * rms * nw[base + 2 * pp];
    const float o = v[2 * pp + 1] * rms * nw[base + 2 * pp + 1];
    row[base + 2 * pp]     = f2bf((e * fr - o * fi) * sc);
    row[base + 2 * pp + 1] = f2bf((e * fi + o * fr) * sc);
  }
}

// ---------------- V transpose: vt[d][tok] = v[tok][d] ----------------
__global__ __launch_bounds__(256)
void transpose_v_k(const unsigned short* __restrict__ v,
                   unsigned short* __restrict__ vt)
{
  __shared__ __align__(16) unsigned short t[64 * 72];
  const int tb = blockIdx.x * 64;
  const int db = blockIdx.y * 64;
  const int tid = threadIdx.x;
#pragma unroll
  for (int it = 0; it < 2; ++it) {
    int c = tid + it * 256;
    int tok = c >> 3, dc = (c & 7) * 8;
    uint4 val = *(const uint4*)(v + (size_t)(tb + tok) * DIMC + db + dc);
    unsigned short tmp[8];
    *(uint4*)tmp = val;
#pragma unroll
    for (int j = 0; j < 8; ++j) t[(dc + j) * 72 + tok] = tmp[j];
  }
  __syncthreads();
#pragma unroll
  for (int it = 0; it < 2; ++it) {
    int c = tid + it * 256;
    int d = c >> 3, tc = (c & 7) * 8;
    *(uint4*)(vt + ((size_t)db + d) * LTOK + tb + tc) = *(const uint4*)&t[d * 72 + tc];
  }
}

// ---------------- MFMA flash attention, S^T layout, split-K for heavy rows ----
// grid 936: bid<720 heavy (qb 18..47, 2 chunks), else light (qb 0..17, 1 chunk).
// Per block: 64 queries x 1 head. S^T = K*Q^T so each lane owns ONE query:
// softmax m/l are per-lane scalars, P^T written as b64, no LDS broadcasts.
__global__ __launch_bounds__(256)
void attn_flash(const unsigned short* __restrict__ q,
                const unsigned short* __restrict__ k,
                const unsigned short* __restrict__ vt,
                unsigned short* __restrict__ ab,
                float* __restrict__ Opart,
                float* __restrict__ mlbuf)
{
  const int bid = blockIdx.x;
  int qb, head, chunk, nchunks;
  if (bid < 720) { const int hb = bid >> 1; qb = 47 - hb / 12; head = hb % 12; chunk = bid & 1; nchunks = 2; }
  else           { const int lb = bid - 720; qb = 17 - lb / 12; head = lb % 12; chunk = 0; nchunks = 1; }

  const int q0 = qb * 64;
  const int qf = qb / 6;
  const int kend = (qf + 1) * FS;
  const int s2 = kend - MAXATTN;
  const bool two = (s2 > FS);
  const int nt1 = (two ? FS : kend) >> 6;
  const int nt  = nt1 + (two ? (MAXATTN >> 6) : 0);
  const int half = nt / nchunks;               // nt even for all 2-chunk rows
  const int tstart = chunk * half, tend = tstart + half;

  const int tid = threadIdx.x;
  const int wave = tid >> 6, lane = tid & 63;
  const int col = lane & 15;       // this lane's query (within wave tile)
  const int g = lane >> 4;         // k-slice group
  const int g4 = g * 4;            // C-layout row base

  __shared__ __align__(16) unsigned short Kl[64 * 136];   // [key][dim]
  __shared__ __align__(16) unsigned short Vtl[128 * 72];  // [d][key]
  __shared__ __align__(16) unsigned short Pl[4][16 * 72]; // per-wave [q][key]

  // Q fragments (B operand): B[n=q=col][k=dim slice]
  bf16x8 qfrag[4];
  {
    const unsigned short* qrow = q + (size_t)(q0 + wave * 16 + col) * DIMC + head * HD;
#pragma unroll
    for (int kk = 0; kk < 4; ++kk)
      qfrag[kk] = *(const bf16x8*)(qrow + kk * 32 + g * 8);
  }

  f32x4 oacc[8] = {};    // O^T: col=q, row=d
  float m = -3.0e38f, l = 0.f;

  auto kbase_of = [&](int t) { return (t < nt1) ? t * 64 : s2 + (t - nt1) * 64; };

  uint4 kr[4], vr[4];
  auto loadt = [&](int kb) {
#pragma unroll
    for (int it = 0; it < 4; ++it) {
      const int c = tid + it * 256;   // 0..1023
      kr[it] = *(const uint4*)(k  + (size_t)(kb + (c >> 4)) * DIMC + head * HD + (c & 15) * 8);
      vr[it] = *(const uint4*)(vt + ((size_t)head * HD + (c >> 3)) * LTOK + kb + (c & 7) * 8);
    }
  };
  loadt(kbase_of(tstart));

  for (int t = tstart; t < tend; ++t) {
#pragma unroll
    for (int it = 0; it < 4; ++it) {
      const int c = tid + it * 256;
      *(uint4*)&Kl[(c >> 4) * 136 + (c & 15) * 8] = kr[it];
      *(uint4*)&Vtl[(c >> 3) * 72 + (c & 7) * 8]  = vr[it];
    }
    __syncthreads();

    if (t + 1 < tend) loadt(kbase_of(t + 1));   // prefetch overlaps compute

    // S^T = K Q^T : C row = key (g4+r), col = q
    f32x4 s[4] = {};
#pragma unroll
    for (int kt = 0; kt < 4; ++kt)
#pragma unroll
      for (int kk = 0; kk < 4; ++kk) {
        bf16x8 kfr = *(const bf16x8*)&Kl[(kt * 16 + col) * 136 + kk * 32 + g * 8];
        s[kt] = __builtin_amdgcn_mfma_f32_16x16x32_bf16(kfr, qfrag[kk], s[kt], 0, 0, 0);
      }

    // online softmax: per-lane (q=col); 16 in-lane values + 2 shuffle hops
    float mx = s[0][0];
#pragma unroll
    for (int kt = 0; kt < 4; ++kt)
#pragma unroll
      for (int r = 0; r < 4; ++r) mx = fmaxf(mx, s[kt][r]);
    mx = fmaxf(mx, __shfl_xor(mx, 16));
    mx = fmaxf(mx, __shfl_xor(mx, 32));
    const float mn = fmaxf(m, mx);
    const float al = exp2f(m - mn);
    m = mn;
    float rs = 0.f;
#pragma unroll
    for (int kt = 0; kt < 4; ++kt) {
      unsigned short pb[4];
#pragma unroll
      for (int r = 0; r < 4; ++r) {
        pb[r] = f2bf(exp2f(s[kt][r] - m));
        rs += bf2f(pb[r]);
      }
      uint2 pk;
      pk.x = (unsigned int)pb[0] | ((unsigned int)pb[1] << 16);
      pk.y = (unsigned int)pb[2] | ((unsigned int)pb[3] << 16);
      *(uint2*)&Pl[wave][col * 72 + kt * 16 + g4] = pk;   // 4 consecutive keys
    }
    rs += __shfl_xor(rs, 16);
    rs += __shfl_xor(rs, 32);
    l = l * al + rs;
#pragma unroll
    for (int dt = 0; dt < 8; ++dt) oacc[dt] *= al;

    // O^T += V^T P^T : A = Vt rows (d), B = P rows (q)
#pragma unroll
    for (int step = 0; step < 2; ++step) {
      bf16x8 pf = *(const bf16x8*)&Pl[wave][col * 72 + step * 32 + g * 8];
#pragma unroll
      for (int dt = 0; dt < 8; ++dt) {
        bf16x8 vf = *(const bf16x8*)&Vtl[(dt * 16 + col) * 72 + step * 32 + g * 8];
        oacc[dt] = __builtin_amdgcn_mfma_f32_16x16x32_bf16(vf, pf, oacc[dt], 0, 0, 0);
      }
    }
    __syncthreads();
  }

  if (nchunks == 1) {
    const float linv = 1.f / l;
    unsigned short* orow = ab + (size_t)(q0 + wave * 16 + col) * DIMC + head * HD;
#pragma unroll
    for (int dt = 0; dt < 8; ++dt) {
      uint2 pk;
      pk.x = (unsigned int)f2bf(oacc[dt][0] * linv) | ((unsigned int)f2bf(oacc[dt][1] * linv) << 16);
      pk.y = (unsigned int)f2bf(oacc[dt][2] * linv) | ((unsigned int)f2bf(oacc[dt][3] * linv) << 16);
      *(uint2*)(orow + dt * 16 + g4) = pk;
    }
  } else {
    const int tokp = q0 + wave * 16 + col - HTOK;
    float* ob = Opart + ((size_t)(chunk * NHT + tokp) * HEADS + head) * HD;
#pragma unroll
    for (int dt = 0; dt < 8; ++dt)
      *(f32x4*)(ob + dt * 16 + g4) = oacc[dt];
    if (lane < 16) {
      float* mlp = mlbuf + 2 * ((size_t)(chunk * NHT + tokp) * HEADS + head);
      mlp[0] = m; mlp[1] = l;
    }
  }
}

// ---------------- merge the two K-chunks for heavy rows ----------------
__global__ __launch_bounds__(384)
void merge_k(const float* __restrict__ Opart, const float* __restrict__ mlbuf,
             unsigned short* __restrict__ ab)
{
  const int tokp = blockIdx.x;           // 0..1919
  const int tid = threadIdx.x;           // 0..383
  const int e = tid * 4;                 // elem in [0,1536)
  const int head = e >> 7;
  const size_t r0 = (size_t)tokp * DIMC + e;
  float4 o0 = *(const float4*)(Opart + r0);
  float4 o1 = *(const float4*)(Opart + (size_t)NHT * DIMC + r0);
  const float* ml0 = mlbuf + 2 * ((size_t)tokp * HEADS + head);
  const float* ml1 = mlbuf + 2 * ((size_t)(NHT + tokp) * HEADS + head);
  const float m0 = ml0[0], l0 = ml0[1], m1 = ml1[0], l1 = ml1[1];
  const float mm = fmaxf(m0, m1);
  const float a0 = exp2f(m0 - mm), a1 = exp2f(m1 - mm);
  const float inv = 1.f / (l0 * a0 + l1 * a1);
  uint2 pk;
  pk.x = (unsigned int)f2bf((o0.x * a0 + o1.x * a1) * inv) |
         ((unsigned int)f2bf((o0.y * a0 + o1.y * a1) * inv) << 16);
  pk.y = (unsigned int)f2bf((o0.z * a0 + o1.z * a1) * inv) |
         ((unsigned int)f2bf((o0.w * a0 + o1.w * a1) * inv) << 16);
  *(uint2*)(ab + (size_t)(HTOK + tokp) * DIMC + e) = pk;
}

// ---------------- launch ----------------
extern "C" void kernel_launch(void* const* d_in, const int* in_sizes, int n_in,
                              void* d_out, int out_size, void* d_ws, size_t ws_size,
                              hipStream_t stream)
{
  (void)in_sizes; (void)n_in; (void)out_size; (void)ws_size;
  const float* x     = (const float*)d_in[0];
  const float* freqs = (const float*)d_in[3];
  const float* wq    = (const float*)d_in[4];
  const float* bq    = (const float*)d_in[5];
  const float* wk    = (const float*)d_in[6];
  const float* bk    = (const float*)d_in[7];
  const float* wv    = (const float*)d_in[8];
  const float* bv    = (const float*)d_in[9];
  const float* wo    = (const float*)d_in[10];
  const float* bo    = (const float*)d_in[11];
  const float* nqw   = (const float*)d_in[12];
  const float* nkw   = (const float*)d_in[13];

  char* ws = (char*)d_ws;
  size_t off = 0;
  auto take = [&](size_t bytes) -> void* {
    void* p = ws + off; off += (bytes + 255) & ~(size_t)255; return p;
  };
  // wob first (must survive attention); xb..wvb are dead after QKV GEMM and
  // are overlaid by Opart (23,592,960 B each, exact match).
  unsigned short* wob = (unsigned short*)take((size_t)DIMC * DIMC * 2);
  unsigned short* qb  = (unsigned short*)take((size_t)LTOK * DIMC * 2);
  unsigned short* kb  = (unsigned short*)take((size_t)LTOK * DIMC * 2);
  unsigned short* vb  = (unsigned short*)take((size_t)LTOK * DIMC * 2);
  unsigned short* ab  = (unsigned short*)take((size_t)LTOK * DIMC * 2);
  unsigned short* vtb = (unsigned short*)take((size_t)LTOK * DIMC * 2);
  unsigned short* xb  = (unsigned short*)take((size_t)LTOK * DIMC * 2);
  unsigned short* wqb = (unsigned short*)take((size_t)DIMC * DIMC * 2);
  unsigned short* wkb = (unsigned short*)take((size_t)DIMC * DIMC * 2);
  unsigned short* wvb = (unsigned short*)take((size_t)DIMC * DIMC * 2);
  float* mlb = (float*)take((size_t)2 * NHT * HEADS * 2 * sizeof(float));
  float* Opart = (float*)xb;   // overlays xb+wqb+wkb+wvb

  cvt_all_k<<<dim3(13824), dim3(256), 0, stream>>>(x, wq, wk, wv, wo,
                                                   xb, wqb, wkb, wvb, wob);

  gemm_nt<false><<<dim3(DIMC / 128, LTOK / 128, 3), dim3(256), 0, stream>>>(
      xb, wqb, wkb, wvb, bq, bk, bv, qb, kb, vb);

  rms_rope_k<<<dim3(LTOK, 2), dim3(256), 0, stream>>>(qb, kb, nqw, nkw, freqs);
  transpose_v_k<<<dim3(LTOK / 64, DIMC / 64), dim3(256), 0, stream>>>(vb, vtb);

  attn_flash<<<dim3(936), dim3(256), 0, stream>>>(qb, kb, vtb, ab, Opart, mlb);
  merge_k<<<dim3(NHT), dim3(384), 0, stream>>>(Opart, mlb, ab);

  gemm_nt<true><<<dim3(DIMC / 128, LTOK / 128, 1), dim3(256), 0, stream>>>(
      ab, wob, wob, wob, bo, bo, bo, d_out, d_out, d_out);
}

// Round 4
// 419.821 us; speedup vs baseline: 1.0325x; 1.0325x over previous
//
#include <hip/hip_runtime.h>
#include <stdint.h>

#define DIMC 1536
#define LTOK 3072
#define HEADS 12
#define HD 128
#define FS 384            // H*W = 16*24
#define MAXATTN 1920
#define HTOK 1152         // first token with qf>=3 (2-chunk rows)
#define NHT 1920          // number of heavy tokens

typedef __attribute__((ext_vector_type(4))) float f32x4;
typedef __attribute__((ext_vector_type(8))) short bf16x8;

__device__ __forceinline__ unsigned short f2bf(float f) {
  union { float f; unsigned int u; } c; c.f = f;
  unsigned int u = c.u + 0x7fffu + ((c.u >> 16) & 1u);   // RNE
  return (unsigned short)(u >> 16);
}
__device__ __forceinline__ float bf2f(unsigned short s) {
  union { unsigned int u; float f; } c; c.u = (unsigned int)s << 16; return c.f;
}

// async global->LDS DMA, 16B per lane; LDS dest must be wave-uniform base +
// lane*16 (our staging offsets are tid*16B -> satisfied).
__device__ __forceinline__ void dma16(const void* g, void* l) {
  __builtin_amdgcn_global_load_lds(
      (const __attribute__((address_space(1))) unsigned int*)g,
      (__attribute__((address_space(3))) unsigned int*)l, 16, 0, 0);
}

// ---------------- fused fp32 -> bf16 conversion for all 5 tensors ----------------
__global__ __launch_bounds__(256)
void cvt_all_k(const float* __restrict__ x, const float* __restrict__ wq,
               const float* __restrict__ wk, const float* __restrict__ wv,
               const float* __restrict__ wo,
               unsigned short* __restrict__ xb, unsigned short* __restrict__ wqb,
               unsigned short* __restrict__ wkb, unsigned short* __restrict__ wvb,
               unsigned short* __restrict__ wob)
{
  const int i = blockIdx.x * 256 + threadIdx.x;      // uint4 index
  const int n0 = LTOK * DIMC / 4;
  const int nw = DIMC * DIMC / 4;
  const float* src; unsigned short* dst; int off;
  if (i < n0) { src = x; dst = xb; off = i; }
  else {
    int j = i - n0; int w = j / nw; off = j - w * nw;
    src = (w == 0) ? wq : (w == 1) ? wk : (w == 2) ? wv : wo;
    dst = (w == 0) ? wqb : (w == 1) ? wkb : (w == 2) ? wvb : wob;
  }
  float4 f = ((const float4*)src)[off];
  uint2 o;
  o.x = (unsigned int)f2bf(f.x) | ((unsigned int)f2bf(f.y) << 16);
  o.y = (unsigned int)f2bf(f.z) | ((unsigned int)f2bf(f.w) << 16);
  ((uint2*)dst)[off] = o;
}

// ---------------- NT GEMM: C[M,N] = A[M,K] * B[N,K]^T + bias ----------------
// 128x128 tile, BK=32; staging via global_load_lds width=16 (m97 pattern).
template <bool F32OUT>
__global__ __launch_bounds__(256)
void gemm_nt(const unsigned short* __restrict__ A,
             const unsigned short* __restrict__ B0,
             const unsigned short* __restrict__ B1,
             const unsigned short* __restrict__ B2,
             const float* __restrict__ bias0,
             const float* __restrict__ bias1,
             const float* __restrict__ bias2,
             void* __restrict__ o0, void* __restrict__ o1, void* __restrict__ o2)
{
  const int z = blockIdx.z;
  const unsigned short* Bw = (z == 0) ? B0 : (z == 1) ? B1 : B2;
  const float* bias = (z == 0) ? bias0 : (z == 1) ? bias1 : bias2;
  void* outp = (z == 0) ? o0 : (z == 1) ? o1 : o2;

  __shared__ __align__(16) unsigned short lA[128 * 32];
  __shared__ __align__(16) unsigned short lB[128 * 32];

  const int tid = threadIdx.x;
  const int wave = tid >> 6;
  const int lane = tid & 63;
  const int m0 = blockIdx.y * 128;
  const int n0 = blockIdx.x * 128;
  const int wm = (wave >> 1) * 64;
  const int wn = (wave & 1) * 64;

  f32x4 acc[4][4] = {};

  const int srow = tid >> 2;         // 0..63
  const int scol = (tid & 3) * 8;    // 0,8,16,24
  const int fr = lane & 15;
  const int fk = (lane >> 4) * 8;

  // LDS staging dest = tid*16B (wave-uniform + lane*16) for each quarter
  unsigned short* la0 = &lA[srow * 32 + scol];
  unsigned short* la1 = &lA[(srow + 64) * 32 + scol];
  unsigned short* lb0 = &lB[srow * 32 + scol];
  unsigned short* lb1 = &lB[(srow + 64) * 32 + scol];
  const unsigned short* ga0 = A  + (size_t)(m0 + srow)      * DIMC + scol;
  const unsigned short* ga1 = A  + (size_t)(m0 + srow + 64) * DIMC + scol;
  const unsigned short* gb0 = Bw + (size_t)(n0 + srow)      * DIMC + scol;
  const unsigned short* gb1 = Bw + (size_t)(n0 + srow + 64) * DIMC + scol;

  for (int k0 = 0; k0 < DIMC; k0 += 32) {
    dma16(ga0 + k0, la0);
    dma16(ga1 + k0, la1);
    dma16(gb0 + k0, lb0);
    dma16(gb1 + k0, lb1);
    __syncthreads();

    bf16x8 af[4], bf[4];
#pragma unroll
    for (int i = 0; i < 4; ++i)
      af[i] = *(const bf16x8*)&lA[(wm + i * 16 + fr) * 32 + fk];
#pragma unroll
    for (int j = 0; j < 4; ++j)
      bf[j] = *(const bf16x8*)&lB[(wn + j * 16 + fr) * 32 + fk];
#pragma unroll
    for (int i = 0; i < 4; ++i)
#pragma unroll
      for (int j = 0; j < 4; ++j)
        acc[i][j] = __builtin_amdgcn_mfma_f32_16x16x32_bf16(af[i], bf[j], acc[i][j], 0, 0, 0);
    __syncthreads();
  }

  const int col = lane & 15;
  const int rb = (lane >> 4) * 4;
#pragma unroll
  for (int j = 0; j < 4; ++j) {
    const int gn = n0 + wn + j * 16 + col;
    const float bv = bias[gn];
#pragma unroll
    for (int i = 0; i < 4; ++i) {
#pragma unroll
      for (int r = 0; r < 4; ++r) {
        const int gm = m0 + wm + i * 16 + rb + r;
        float val = acc[i][j][r] + bv;
        if (F32OUT)
          ((float*)outp)[(size_t)gm * DIMC + gn] = val;
        else
          ((unsigned short*)outp)[(size_t)gm * DIMC + gn] = f2bf(val);
      }
    }
  }
}

// ---------------- rmsnorm + 3D RoPE, in place; q additionally scaled ----------------
// q *= 1/sqrt(HD) * log2(e)  (folded so attention softmax runs in exp2 domain)
__global__ __launch_bounds__(256)
void rms_rope_k(unsigned short* __restrict__ q, unsigned short* __restrict__ k,
                const float* __restrict__ nqw, const float* __restrict__ nkw,
                const float* __restrict__ freqs)
{
  const int tok = blockIdx.x;
  const int which = blockIdx.y;
  unsigned short* row = (which ? k : q) + (size_t)tok * DIMC;
  const float* nw = which ? nkw : nqw;
  const float sc = which ? 1.f : (0.08838834764831845f * 1.4426950408889634f);
  const int tid = threadIdx.x;
  const int base = tid * 6;

  float v[6];
  float ss = 0.f;
#pragma unroll
  for (int j = 0; j < 6; ++j) {
    v[j] = bf2f(row[base + j]);
    ss += v[j] * v[j];
  }
#pragma unroll
  for (int off = 1; off < 64; off <<= 1) ss += __shfl_xor(ss, off);
  __shared__ float wsum[4];
  if ((tid & 63) == 0) wsum[tid >> 6] = ss;
  __syncthreads();
  const float total = wsum[0] + wsum[1] + wsum[2] + wsum[3];
  const float rms = rsqrtf(total * (1.f / DIMC) + 1e-6f);

  const int f = tok / FS;
  const int rem = tok - f * FS;
  const int h = rem / 24;
  const int w = rem - h * 24;

#pragma unroll
  for (int pp = 0; pp < 3; ++pp) {
    const int P = (base >> 1) + pp;
    const int p = P & 63;
    const int t = (p < 22) ? f : ((p < 43) ? h : w);
    const float fr = freqs[t * 128 + p * 2];
    const float fi = freqs[t * 128 + p * 2 + 1];
    const float e = v[2 * pp]     * rms * nw[base + 2 * pp];
    const float o = v[2 * pp + 1] * rms * nw[base + 2 * pp + 1];
    row[base + 2 * pp]     = f2bf((e * fr - o * fi) * sc);
    row[base + 2 * pp + 1] = f2bf((e * fi + o * fr) * sc);
  }
}

// ---------------- V transpose: vt[d][tok] = v[tok][d] ----------------
__global__ __launch_bounds__(256)
void transpose_v_k(const unsigned short* __restrict__ v,
                   unsigned short* __restrict__ vt)
{
  __shared__ __align__(16) unsigned short t[64 * 72];
  const int tb = blockIdx.x * 64;
  const int db = blockIdx.y * 64;
  const int tid = threadIdx.x;
#pragma unroll
  for (int it = 0; it < 2; ++it) {
    int c = tid + it * 256;
    int tok = c >> 3, dc = (c & 7) * 8;
    uint4 val = *(const uint4*)(v + (size_t)(tb + tok) * DIMC + db + dc);
    unsigned short tmp[8];
    *(uint4*)tmp = val;
#pragma unroll
    for (int j = 0; j < 8; ++j) t[(dc + j) * 72 + tok] = tmp[j];
  }
  __syncthreads();
#pragma unroll
  for (int it = 0; it < 2; ++it) {
    int c = tid + it * 256;
    int d = c >> 3, tc = (c & 7) * 8;
    *(uint4*)(vt + ((size_t)db + d) * LTOK + tb + tc) = *(const uint4*)&t[d * 72 + tc];
  }
}

// ---------------- MFMA flash attention, S^T layout, split-K for heavy rows ----
// grid 936: bid<720 heavy (qb 18..47, 2 chunks), else light (qb 0..17, 1 chunk).
// S^T = K*Q^T so each lane owns ONE query: softmax m/l per-lane scalars.
// __launch_bounds__(256,2): allow ~256 VGPR so the tile prefetch (kr/vr) does
// NOT spill to scratch (R2 regression: 406 MB scratch writes at 84-VGPR cap).
// Occupancy is LDS-bound (44KB -> 3 blocks/CU) either way.
__global__ __launch_bounds__(256, 2)
void attn_flash(const unsigned short* __restrict__ q,
                const unsigned short* __restrict__ k,
                const unsigned short* __restrict__ vt,
                unsigned short* __restrict__ ab,
                float* __restrict__ Opart,
                float* __restrict__ mlbuf)
{
  const int bid = blockIdx.x;
  int qb, head, chunk, nchunks;
  if (bid < 720) { const int hb = bid >> 1; qb = 47 - hb / 12; head = hb % 12; chunk = bid & 1; nchunks = 2; }
  else           { const int lb = bid - 720; qb = 17 - lb / 12; head = lb % 12; chunk = 0; nchunks = 1; }

  const int q0 = qb * 64;
  const int qf = qb / 6;
  const int kend = (qf + 1) * FS;
  const int s2 = kend - MAXATTN;
  const bool two = (s2 > FS);
  const int nt1 = (two ? FS : kend) >> 6;
  const int nt  = nt1 + (two ? (MAXATTN >> 6) : 0);
  const int half = nt / nchunks;               // nt even for all 2-chunk rows
  const int tstart = chunk * half, tend = tstart + half;

  const int tid = threadIdx.x;
  const int wave = tid >> 6, lane = tid & 63;
  const int col = lane & 15;       // this lane's query (within wave tile)
  const int g = lane >> 4;         // k-slice group
  const int g4 = g * 4;            // C-layout row base

  __shared__ __align__(16) unsigned short Kl[64 * 136];   // [key][dim]
  __shared__ __align__(16) unsigned short Vtl[128 * 72];  // [d][key]
  __shared__ __align__(16) unsigned short Pl[4][16 * 72]; // per-wave [q][key]

  // Q fragments (B operand): B[n=q=col][k=dim slice]
  bf16x8 qfrag[4];
  {
    const unsigned short* qrow = q + (size_t)(q0 + wave * 16 + col) * DIMC + head * HD;
#pragma unroll
    for (int kk = 0; kk < 4; ++kk)
      qfrag[kk] = *(const bf16x8*)(qrow + kk * 32 + g * 8);
  }

  f32x4 oacc[8] = {};    // O^T: col=q, row=d
  float m = -3.0e38f, l = 0.f;

  auto kbase_of = [&](int t) { return (t < nt1) ? t * 64 : s2 + (t - nt1) * 64; };

  uint4 kr[4], vr[4];
  auto loadt = [&](int kb) {
#pragma unroll
    for (int it = 0; it < 4; ++it) {
      const int c = tid + it * 256;   // 0..1023
      kr[it] = *(const uint4*)(k  + (size_t)(kb + (c >> 4)) * DIMC + head * HD + (c & 15) * 8);
      vr[it] = *(const uint4*)(vt + ((size_t)head * HD + (c >> 3)) * LTOK + kb + (c & 7) * 8);
    }
  };
  loadt(kbase_of(tstart));

  for (int t = tstart; t < tend; ++t) {
#pragma unroll
    for (int it = 0; it < 4; ++it) {
      const int c = tid + it * 256;
      *(uint4*)&Kl[(c >> 4) * 136 + (c & 15) * 8] = kr[it];
      *(uint4*)&Vtl[(c >> 3) * 72 + (c & 7) * 8]  = vr[it];
    }
    __syncthreads();

    if (t + 1 < tend) loadt(kbase_of(t + 1));   // prefetch overlaps compute

    // S^T = K Q^T : C row = key (g4+r), col = q
    f32x4 s[4] = {};
#pragma unroll
    for (int kt = 0; kt < 4; ++kt)
#pragma unroll
      for (int kk = 0; kk < 4; ++kk) {
        bf16x8 kfr = *(const bf16x8*)&Kl[(kt * 16 + col) * 136 + kk * 32 + g * 8];
        s[kt] = __builtin_amdgcn_mfma_f32_16x16x32_bf16(kfr, qfrag[kk], s[kt], 0, 0, 0);
      }

    // online softmax: per-lane (q=col); 16 in-lane values + 2 shuffle hops
    float mx = s[0][0];
#pragma unroll
    for (int kt = 0; kt < 4; ++kt)
#pragma unroll
      for (int r = 0; r < 4; ++r) mx = fmaxf(mx, s[kt][r]);
    mx = fmaxf(mx, __shfl_xor(mx, 16));
    mx = fmaxf(mx, __shfl_xor(mx, 32));
    const float mn = fmaxf(m, mx);
    const float al = exp2f(m - mn);
    m = mn;
    float rs = 0.f;
#pragma unroll
    for (int kt = 0; kt < 4; ++kt) {
      unsigned short pb[4];
#pragma unroll
      for (int r = 0; r < 4; ++r) {
        pb[r] = f2bf(exp2f(s[kt][r] - m));
        rs += bf2f(pb[r]);
      }
      uint2 pk;
      pk.x = (unsigned int)pb[0] | ((unsigned int)pb[1] << 16);
      pk.y = (unsigned int)pb[2] | ((unsigned int)pb[3] << 16);
      *(uint2*)&Pl[wave][col * 72 + kt * 16 + g4] = pk;   // 4 consecutive keys
    }
    rs += __shfl_xor(rs, 16);
    rs += __shfl_xor(rs, 32);
    l = l * al + rs;
#pragma unroll
    for (int dt = 0; dt < 8; ++dt) oacc[dt] *= al;

    // O^T += V^T P^T : A = Vt rows (d), B = P rows (q)
#pragma unroll
    for (int step = 0; step < 2; ++step) {
      bf16x8 pf = *(const bf16x8*)&Pl[wave][col * 72 + step * 32 + g * 8];
#pragma unroll
      for (int dt = 0; dt < 8; ++dt) {
        bf16x8 vf = *(const bf16x8*)&Vtl[(dt * 16 + col) * 72 + step * 32 + g * 8];
        oacc[dt] = __builtin_amdgcn_mfma_f32_16x16x32_bf16(vf, pf, oacc[dt], 0, 0, 0);
      }
    }
    __syncthreads();
  }

  if (nchunks == 1) {
    const float linv = 1.f / l;
    unsigned short* orow = ab + (size_t)(q0 + wave * 16 + col) * DIMC + head * HD;
#pragma unroll
    for (int dt = 0; dt < 8; ++dt) {
      uint2 pk;
      pk.x = (unsigned int)f2bf(oacc[dt][0] * linv) | ((unsigned int)f2bf(oacc[dt][1] * linv) << 16);
      pk.y = (unsigned int)f2bf(oacc[dt][2] * linv) | ((unsigned int)f2bf(oacc[dt][3] * linv) << 16);
      *(uint2*)(orow + dt * 16 + g4) = pk;
    }
  } else {
    const int tokp = q0 + wave * 16 + col - HTOK;
    float* ob = Opart + ((size_t)(chunk * NHT + tokp) * HEADS + head) * HD;
#pragma unroll
    for (int dt = 0; dt < 8; ++dt)
      *(f32x4*)(ob + dt * 16 + g4) = oacc[dt];
    if (lane < 16) {
      float* mlp = mlbuf + 2 * ((size_t)(chunk * NHT + tokp) * HEADS + head);
      mlp[0] = m; mlp[1] = l;
    }
  }
}

// ---------------- merge the two K-chunks for heavy rows ----------------
__global__ __launch_bounds__(384)
void merge_k(const float* __restrict__ Opart, const float* __restrict__ mlbuf,
             unsigned short* __restrict__ ab)
{
  const int tokp = blockIdx.x;           // 0..1919
  const int tid = threadIdx.x;           // 0..383
  const int e = tid * 4;                 // elem in [0,1536)
  const int head = e >> 7;
  const size_t r0 = (size_t)tokp * DIMC + e;
  float4 o0 = *(const float4*)(Opart + r0);
  float4 o1 = *(const float4*)(Opart + (size_t)NHT * DIMC + r0);
  const float* ml0 = mlbuf + 2 * ((size_t)tokp * HEADS + head);
  const float* ml1 = mlbuf + 2 * ((size_t)(NHT + tokp) * HEADS + head);
  const float m0 = ml0[0], l0 = ml0[1], m1 = ml1[0], l1 = ml1[1];
  const float mm = fmaxf(m0, m1);
  const float a0 = exp2f(m0 - mm), a1 = exp2f(m1 - mm);
  const float inv = 1.f / (l0 * a0 + l1 * a1);
  uint2 pk;
  pk.x = (unsigned int)f2bf((o0.x * a0 + o1.x * a1) * inv) |
         ((unsigned int)f2bf((o0.y * a0 + o1.y * a1) * inv) << 16);
  pk.y = (unsigned int)f2bf((o0.z * a0 + o1.z * a1) * inv) |
         ((unsigned int)f2bf((o0.w * a0 + o1.w * a1) * inv) << 16);
  *(uint2*)(ab + (size_t)(HTOK + tokp) * DIMC + e) = pk;
}

// ---------------- launch ----------------
extern "C" void kernel_launch(void* const* d_in, const int* in_sizes, int n_in,
                              void* d_out, int out_size, void* d_ws, size_t ws_size,
                              hipStream_t stream)
{
  (void)in_sizes; (void)n_in; (void)out_size; (void)ws_size;
  const float* x     = (const float*)d_in[0];
  const float* freqs = (const float*)d_in[3];
  const float* wq    = (const float*)d_in[4];
  const float* bq    = (const float*)d_in[5];
  const float* wk    = (const float*)d_in[6];
  const float* bk    = (const float*)d_in[7];
  const float* wv    = (const float*)d_in[8];
  const float* bv    = (const float*)d_in[9];
  const float* wo    = (const float*)d_in[10];
  const float* bo    = (const float*)d_in[11];
  const float* nqw   = (const float*)d_in[12];
  const float* nkw   = (const float*)d_in[13];

  char* ws = (char*)d_ws;
  size_t off = 0;
  auto take = [&](size_t bytes) -> void* {
    void* p = ws + off; off += (bytes + 255) & ~(size_t)255; return p;
  };
  // wob first (must survive attention); xb..wvb are dead after QKV GEMM and
  // are overlaid by Opart (23,592,960 B, exact match).
  unsigned short* wob = (unsigned short*)take((size_t)DIMC * DIMC * 2);
  unsigned short* qb  = (unsigned short*)take((size_t)LTOK * DIMC * 2);
  unsigned short* kb  = (unsigned short*)take((size_t)LTOK * DIMC * 2);
  unsigned short* vb  = (unsigned short*)take((size_t)LTOK * DIMC * 2);
  unsigned short* ab  = (unsigned short*)take((size_t)LTOK * DIMC * 2);
  unsigned short* vtb = (unsigned short*)take((size_t)LTOK * DIMC * 2);
  unsigned short* xb  = (unsigned short*)take((size_t)LTOK * DIMC * 2);
  unsigned short* wqb = (unsigned short*)take((size_t)DIMC * DIMC * 2);
  unsigned short* wkb = (unsigned short*)take((size_t)DIMC * DIMC * 2);
  unsigned short* wvb = (unsigned short*)take((size_t)DIMC * DIMC * 2);
  float* mlb = (float*)take((size_t)2 * NHT * HEADS * 2 * sizeof(float));
  float* Opart = (float*)xb;   // overlays xb+wqb+wkb+wvb

  cvt_all_k<<<dim3(13824), dim3(256), 0, stream>>>(x, wq, wk, wv, wo,
                                                   xb, wqb, wkb, wvb, wob);

  gemm_nt<false><<<dim3(DIMC / 128, LTOK / 128, 3), dim3(256), 0, stream>>>(
      xb, wqb, wkb, wvb, bq, bk, bv, qb, kb, vb);

  rms_rope_k<<<dim3(LTOK, 2), dim3(256), 0, stream>>>(qb, kb, nqw, nkw, freqs);
  transpose_v_k<<<dim3(LTOK / 64, DIMC / 64), dim3(256), 0, stream>>>(vb, vtb);

  attn_flash<<<dim3(936), dim3(256), 0, stream>>>(qb, kb, vtb, ab, Opart, mlb);
  merge_k<<<dim3(NHT), dim3(384), 0, stream>>>(Opart, mlb, ab);

  gemm_nt<true><<<dim3(DIMC / 128, LTOK / 128, 1), dim3(256), 0, stream>>>(
      ab, wob, wob, wob, bo, bo, bo, d_out, d_out, d_out);
}

// Round 5
// 331.124 us; speedup vs baseline: 1.3091x; 1.2679x over previous
//
#include <hip/hip_runtime.h>
#include <stdint.h>

#define DIMC 1536
#define LTOK 3072
#define HEADS 12
#define HD 128
#define FS 384            // H*W = 16*24
#define MAXATTN 1920
#define HTOK 1152         // first token with qf>=3 (2-chunk rows)
#define NHT 1920          // number of heavy tokens

typedef __attribute__((ext_vector_type(4))) float f32x4;
typedef __attribute__((ext_vector_type(8))) short bf16x8;

__device__ __forceinline__ unsigned short f2bf(float f) {
  union { float f; unsigned int u; } c; c.f = f;
  unsigned int u = c.u + 0x7fffu + ((c.u >> 16) & 1u);   // RNE
  return (unsigned short)(u >> 16);
}
__device__ __forceinline__ float bf2f(unsigned short s) {
  union { unsigned int u; float f; } c; c.u = (unsigned int)s << 16; return c.f;
}

// async global->LDS DMA, 16B per lane; LDS dest must be wave-uniform base +
// lane*16 (our staging offsets are tid*16B -> satisfied).
__device__ __forceinline__ void dma16(const void* g, void* l) {
  __builtin_amdgcn_global_load_lds(
      (const __attribute__((address_space(1))) unsigned int*)g,
      (__attribute__((address_space(3))) unsigned int*)l, 16, 0, 0);
}

// ---------------- fused fp32 -> bf16 conversion for all 5 tensors ----------------
__global__ __launch_bounds__(256)
void cvt_all_k(const float* __restrict__ x, const float* __restrict__ wq,
               const float* __restrict__ wk, const float* __restrict__ wv,
               const float* __restrict__ wo,
               unsigned short* __restrict__ xb, unsigned short* __restrict__ wqb,
               unsigned short* __restrict__ wkb, unsigned short* __restrict__ wvb,
               unsigned short* __restrict__ wob)
{
  const int i = blockIdx.x * 256 + threadIdx.x;      // uint4 index
  const int n0 = LTOK * DIMC / 4;
  const int nw = DIMC * DIMC / 4;
  const float* src; unsigned short* dst; int off;
  if (i < n0) { src = x; dst = xb; off = i; }
  else {
    int j = i - n0; int w = j / nw; off = j - w * nw;
    src = (w == 0) ? wq : (w == 1) ? wk : (w == 2) ? wv : wo;
    dst = (w == 0) ? wqb : (w == 1) ? wkb : (w == 2) ? wvb : wob;
  }
  float4 f = ((const float4*)src)[off];
  uint2 o;
  o.x = (unsigned int)f2bf(f.x) | ((unsigned int)f2bf(f.y) << 16);
  o.y = (unsigned int)f2bf(f.z) | ((unsigned int)f2bf(f.w) << 16);
  ((uint2*)dst)[off] = o;
}

// ---------------- NT GEMM: C[M,N] = A[M,K] * B[N,K]^T + bias ----------------
// 128x128 tile, BK=32; staging via global_load_lds width=16 (m97 pattern).
template <bool F32OUT>
__global__ __launch_bounds__(256)
void gemm_nt(const unsigned short* __restrict__ A,
             const unsigned short* __restrict__ B0,
             const unsigned short* __restrict__ B1,
             const unsigned short* __restrict__ B2,
             const float* __restrict__ bias0,
             const float* __restrict__ bias1,
             const float* __restrict__ bias2,
             void* __restrict__ o0, void* __restrict__ o1, void* __restrict__ o2)
{
  const int z = blockIdx.z;
  const unsigned short* Bw = (z == 0) ? B0 : (z == 1) ? B1 : B2;
  const float* bias = (z == 0) ? bias0 : (z == 1) ? bias1 : bias2;
  void* outp = (z == 0) ? o0 : (z == 1) ? o1 : o2;

  __shared__ __align__(16) unsigned short lA[128 * 32];
  __shared__ __align__(16) unsigned short lB[128 * 32];

  const int tid = threadIdx.x;
  const int wave = tid >> 6;
  const int lane = tid & 63;
  const int m0 = blockIdx.y * 128;
  const int n0 = blockIdx.x * 128;
  const int wm = (wave >> 1) * 64;
  const int wn = (wave & 1) * 64;

  f32x4 acc[4][4] = {};

  const int srow = tid >> 2;         // 0..63
  const int scol = (tid & 3) * 8;    // 0,8,16,24
  const int fr = lane & 15;
  const int fk = (lane >> 4) * 8;

  unsigned short* la0 = &lA[srow * 32 + scol];
  unsigned short* la1 = &lA[(srow + 64) * 32 + scol];
  unsigned short* lb0 = &lB[srow * 32 + scol];
  unsigned short* lb1 = &lB[(srow + 64) * 32 + scol];
  const unsigned short* ga0 = A  + (size_t)(m0 + srow)      * DIMC + scol;
  const unsigned short* ga1 = A  + (size_t)(m0 + srow + 64) * DIMC + scol;
  const unsigned short* gb0 = Bw + (size_t)(n0 + srow)      * DIMC + scol;
  const unsigned short* gb1 = Bw + (size_t)(n0 + srow + 64) * DIMC + scol;

  for (int k0 = 0; k0 < DIMC; k0 += 32) {
    dma16(ga0 + k0, la0);
    dma16(ga1 + k0, la1);
    dma16(gb0 + k0, lb0);
    dma16(gb1 + k0, lb1);
    __syncthreads();

    bf16x8 af[4], bf[4];
#pragma unroll
    for (int i = 0; i < 4; ++i)
      af[i] = *(const bf16x8*)&lA[(wm + i * 16 + fr) * 32 + fk];
#pragma unroll
    for (int j = 0; j < 4; ++j)
      bf[j] = *(const bf16x8*)&lB[(wn + j * 16 + fr) * 32 + fk];
#pragma unroll
    for (int i = 0; i < 4; ++i)
#pragma unroll
      for (int j = 0; j < 4; ++j)
        acc[i][j] = __builtin_amdgcn_mfma_f32_16x16x32_bf16(af[i], bf[j], acc[i][j], 0, 0, 0);
    __syncthreads();
  }

  const int col = lane & 15;
  const int rb = (lane >> 4) * 4;
#pragma unroll
  for (int j = 0; j < 4; ++j) {
    const int gn = n0 + wn + j * 16 + col;
    const float bv = bias[gn];
#pragma unroll
    for (int i = 0; i < 4; ++i) {
#pragma unroll
      for (int r = 0; r < 4; ++r) {
        const int gm = m0 + wm + i * 16 + rb + r;
        float val = acc[i][j][r] + bv;
        if (F32OUT)
          ((float*)outp)[(size_t)gm * DIMC + gn] = val;
        else
          ((unsigned short*)outp)[(size_t)gm * DIMC + gn] = f2bf(val);
      }
    }
  }
}

// ---------------- rmsnorm + 3D RoPE, in place; q additionally scaled ----------------
// q *= 1/sqrt(HD) * log2(e)  (folded so attention softmax runs in exp2 domain)
__global__ __launch_bounds__(256)
void rms_rope_k(unsigned short* __restrict__ q, unsigned short* __restrict__ k,
                const float* __restrict__ nqw, const float* __restrict__ nkw,
                const float* __restrict__ freqs)
{
  const int tok = blockIdx.x;
  const int which = blockIdx.y;
  unsigned short* row = (which ? k : q) + (size_t)tok * DIMC;
  const float* nw = which ? nkw : nqw;
  const float sc = which ? 1.f : (0.08838834764831845f * 1.4426950408889634f);
  const int tid = threadIdx.x;
  const int base = tid * 6;

  float v[6];
  float ss = 0.f;
#pragma unroll
  for (int j = 0; j < 6; ++j) {
    v[j] = bf2f(row[base + j]);
    ss += v[j] * v[j];
  }
#pragma unroll
  for (int off = 1; off < 64; off <<= 1) ss += __shfl_xor(ss, off);
  __shared__ float wsum[4];
  if ((tid & 63) == 0) wsum[tid >> 6] = ss;
  __syncthreads();
  const float total = wsum[0] + wsum[1] + wsum[2] + wsum[3];
  const float rms = rsqrtf(total * (1.f / DIMC) + 1e-6f);

  const int f = tok / FS;
  const int rem = tok - f * FS;
  const int h = rem / 24;
  const int w = rem - h * 24;

#pragma unroll
  for (int pp = 0; pp < 3; ++pp) {
    const int P = (base >> 1) + pp;
    const int p = P & 63;
    const int t = (p < 22) ? f : ((p < 43) ? h : w);
    const float fr = freqs[t * 128 + p * 2];
    const float fi = freqs[t * 128 + p * 2 + 1];
    const float e = v[2 * pp]     * rms * nw[base + 2 * pp];
    const float o = v[2 * pp + 1] * rms * nw[base + 2 * pp + 1];
    row[base + 2 * pp]     = f2bf((e * fr - o * fi) * sc);
    row[base + 2 * pp + 1] = f2bf((e * fi + o * fr) * sc);
  }
}

// ---------------- V transpose: vt[d][tok] = v[tok][d] ----------------
__global__ __launch_bounds__(256)
void transpose_v_k(const unsigned short* __restrict__ v,
                   unsigned short* __restrict__ vt)
{
  __shared__ __align__(16) unsigned short t[64 * 72];
  const int tb = blockIdx.x * 64;
  const int db = blockIdx.y * 64;
  const int tid = threadIdx.x;
#pragma unroll
  for (int it = 0; it < 2; ++it) {
    int c = tid + it * 256;
    int tok = c >> 3, dc = (c & 7) * 8;
    uint4 val = *(const uint4*)(v + (size_t)(tb + tok) * DIMC + db + dc);
    unsigned short tmp[8];
    *(uint4*)tmp = val;
#pragma unroll
    for (int j = 0; j < 8; ++j) t[(dc + j) * 72 + tok] = tmp[j];
  }
  __syncthreads();
#pragma unroll
  for (int it = 0; it < 2; ++it) {
    int c = tid + it * 256;
    int d = c >> 3, tc = (c & 7) * 8;
    *(uint4*)(vt + ((size_t)db + d) * LTOK + tb + tc) = *(const uint4*)&t[d * 72 + tc];
  }
}

// ---------------- MFMA flash attention, S^T layout, split-K for heavy rows ----
// grid 936: bid<720 heavy (qb 18..47, 2 chunks), else light (qb 0..17, 1 chunk).
// S^T = K*Q^T so each lane owns ONE query: softmax m/l per-lane scalars.
// Prefetch uses 8 individually-NAMED uint4 scalars (no arrays, no lambda):
// R2/R3 regression was failed SROA -> the kr[]/vr[] allocas lived in scratch
// (390 MB of scratch traffic, VGPR_Count 72). Named scalars force SSA regs.
__global__ __launch_bounds__(256, 2)
void attn_flash(const unsigned short* __restrict__ q,
                const unsigned short* __restrict__ k,
                const unsigned short* __restrict__ vt,
                unsigned short* __restrict__ ab,
                float* __restrict__ Opart,
                float* __restrict__ mlbuf)
{
  const int bid = blockIdx.x;
  int qb, head, chunk, nchunks;
  if (bid < 720) { const int hb = bid >> 1; qb = 47 - hb / 12; head = hb % 12; chunk = bid & 1; nchunks = 2; }
  else           { const int lb = bid - 720; qb = 17 - lb / 12; head = lb % 12; chunk = 0; nchunks = 1; }

  const int q0 = qb * 64;
  const int qf = qb / 6;
  const int kend = (qf + 1) * FS;
  const int s2 = kend - MAXATTN;
  const bool two = (s2 > FS);
  const int nt1 = (two ? FS : kend) >> 6;
  const int nt  = nt1 + (two ? (MAXATTN >> 6) : 0);
  const int half = nt / nchunks;               // nt even for all 2-chunk rows
  const int tstart = chunk * half, tend = tstart + half;

  const int tid = threadIdx.x;
  const int wave = tid >> 6, lane = tid & 63;
  const int col = lane & 15;       // this lane's query (within wave tile)
  const int g = lane >> 4;         // k-slice group
  const int g4 = g * 4;            // C-layout row base

  __shared__ __align__(16) unsigned short Kl[64 * 136];   // [key][dim]
  __shared__ __align__(16) unsigned short Vtl[128 * 72];  // [d][key]
  __shared__ __align__(16) unsigned short Pl[4][16 * 72]; // per-wave [q][key]

  // Q fragments (B operand): B[n=q=col][k=dim slice]
  bf16x8 qfrag[4];
  {
    const unsigned short* qrow = q + (size_t)(q0 + wave * 16 + col) * DIMC + head * HD;
#pragma unroll
    for (int kk = 0; kk < 4; ++kk)
      qfrag[kk] = *(const bf16x8*)(qrow + kk * 32 + g * 8);
  }

  f32x4 oacc[8] = {};    // O^T: col=q, row=d
  float m = -3.0e38f, l = 0.f;

  // per-thread staging bases (compile-time-constant offsets between quarters)
  const unsigned short* kgb = k  + (size_t)(tid >> 4) * DIMC + head * HD + (tid & 15) * 8;
  const unsigned short* vgb = vt + ((size_t)head * HD + (tid >> 3)) * LTOK + (tid & 7) * 8;
  unsigned short* kls = &Kl[(tid >> 4) * 136 + (tid & 15) * 8];
  unsigned short* vls = &Vtl[(tid >> 3) * 72 + (tid & 7) * 8];

  uint4 kr0, kr1, kr2, kr3, vr0, vr1, vr2, vr3;
  {
    const int kb = (tstart < nt1) ? tstart * 64 : s2 + (tstart - nt1) * 64;
    const unsigned short* kp = kgb + (size_t)kb * DIMC;
    kr0 = *(const uint4*)(kp);
    kr1 = *(const uint4*)(kp + (size_t)16 * DIMC);
    kr2 = *(const uint4*)(kp + (size_t)32 * DIMC);
    kr3 = *(const uint4*)(kp + (size_t)48 * DIMC);
    const unsigned short* vp = vgb + kb;
    vr0 = *(const uint4*)(vp);
    vr1 = *(const uint4*)(vp + (size_t)32 * LTOK);
    vr2 = *(const uint4*)(vp + (size_t)64 * LTOK);
    vr3 = *(const uint4*)(vp + (size_t)96 * LTOK);
  }

  for (int t = tstart; t < tend; ++t) {
    *(uint4*)(kls)            = kr0;
    *(uint4*)(kls + 16 * 136) = kr1;
    *(uint4*)(kls + 32 * 136) = kr2;
    *(uint4*)(kls + 48 * 136) = kr3;
    *(uint4*)(vls)            = vr0;
    *(uint4*)(vls + 32 * 72)  = vr1;
    *(uint4*)(vls + 64 * 72)  = vr2;
    *(uint4*)(vls + 96 * 72)  = vr3;
    __syncthreads();

    if (t + 1 < tend) {   // prefetch next tile; overlaps with compute below
      const int kb = (t + 1 < nt1) ? (t + 1) * 64 : s2 + (t + 1 - nt1) * 64;
      const unsigned short* kp = kgb + (size_t)kb * DIMC;
      kr0 = *(const uint4*)(kp);
      kr1 = *(const uint4*)(kp + (size_t)16 * DIMC);
      kr2 = *(const uint4*)(kp + (size_t)32 * DIMC);
      kr3 = *(const uint4*)(kp + (size_t)48 * DIMC);
      const unsigned short* vp = vgb + kb;
      vr0 = *(const uint4*)(vp);
      vr1 = *(const uint4*)(vp + (size_t)32 * LTOK);
      vr2 = *(const uint4*)(vp + (size_t)64 * LTOK);
      vr3 = *(const uint4*)(vp + (size_t)96 * LTOK);
    }

    // S^T = K Q^T : C row = key (g4+r), col = q
    f32x4 s[4] = {};
#pragma unroll
    for (int kt = 0; kt < 4; ++kt)
#pragma unroll
      for (int kk = 0; kk < 4; ++kk) {
        bf16x8 kfr = *(const bf16x8*)&Kl[(kt * 16 + col) * 136 + kk * 32 + g * 8];
        s[kt] = __builtin_amdgcn_mfma_f32_16x16x32_bf16(kfr, qfrag[kk], s[kt], 0, 0, 0);
      }

    // online softmax: per-lane (q=col); 16 in-lane values + 2 shuffle hops
    float mx = s[0][0];
#pragma unroll
    for (int kt = 0; kt < 4; ++kt)
#pragma unroll
      for (int r = 0; r < 4; ++r) mx = fmaxf(mx, s[kt][r]);
    mx = fmaxf(mx, __shfl_xor(mx, 16));
    mx = fmaxf(mx, __shfl_xor(mx, 32));
    const float mn = fmaxf(m, mx);
    const float al = exp2f(m - mn);
    m = mn;
    float rs = 0.f;
#pragma unroll
    for (int kt = 0; kt < 4; ++kt) {
      const unsigned short p0 = f2bf(exp2f(s[kt][0] - m));
      const unsigned short p1 = f2bf(exp2f(s[kt][1] - m));
      const unsigned short p2 = f2bf(exp2f(s[kt][2] - m));
      const unsigned short p3 = f2bf(exp2f(s[kt][3] - m));
      rs += bf2f(p0) + bf2f(p1) + bf2f(p2) + bf2f(p3);
      uint2 pk;
      pk.x = (unsigned int)p0 | ((unsigned int)p1 << 16);
      pk.y = (unsigned int)p2 | ((unsigned int)p3 << 16);
      *(uint2*)&Pl[wave][col * 72 + kt * 16 + g4] = pk;   // 4 consecutive keys
    }
    rs += __shfl_xor(rs, 16);
    rs += __shfl_xor(rs, 32);
    l = l * al + rs;
#pragma unroll
    for (int dt = 0; dt < 8; ++dt) oacc[dt] *= al;

    // O^T += V^T P^T : A = Vt rows (d), B = P rows (q)
#pragma unroll
    for (int step = 0; step < 2; ++step) {
      bf16x8 pf = *(const bf16x8*)&Pl[wave][col * 72 + step * 32 + g * 8];
#pragma unroll
      for (int dt = 0; dt < 8; ++dt) {
        bf16x8 vf = *(const bf16x8*)&Vtl[(dt * 16 + col) * 72 + step * 32 + g * 8];
        oacc[dt] = __builtin_amdgcn_mfma_f32_16x16x32_bf16(vf, pf, oacc[dt], 0, 0, 0);
      }
    }
    __syncthreads();
  }

  if (nchunks == 1) {
    const float linv = 1.f / l;
    unsigned short* orow = ab + (size_t)(q0 + wave * 16 + col) * DIMC + head * HD;
#pragma unroll
    for (int dt = 0; dt < 8; ++dt) {
      uint2 pk;
      pk.x = (unsigned int)f2bf(oacc[dt][0] * linv) | ((unsigned int)f2bf(oacc[dt][1] * linv) << 16);
      pk.y = (unsigned int)f2bf(oacc[dt][2] * linv) | ((unsigned int)f2bf(oacc[dt][3] * linv) << 16);
      *(uint2*)(orow + dt * 16 + g4) = pk;
    }
  } else {
    const int tokp = q0 + wave * 16 + col - HTOK;
    float* ob = Opart + ((size_t)(chunk * NHT + tokp) * HEADS + head) * HD;
#pragma unroll
    for (int dt = 0; dt < 8; ++dt)
      *(f32x4*)(ob + dt * 16 + g4) = oacc[dt];
    if (lane < 16) {
      float* mlp = mlbuf + 2 * ((size_t)(chunk * NHT + tokp) * HEADS + head);
      mlp[0] = m; mlp[1] = l;
    }
  }
}

// ---------------- merge the two K-chunks for heavy rows ----------------
__global__ __launch_bounds__(384)
void merge_k(const float* __restrict__ Opart, const float* __restrict__ mlbuf,
             unsigned short* __restrict__ ab)
{
  const int tokp = blockIdx.x;           // 0..1919
  const int tid = threadIdx.x;           // 0..383
  const int e = tid * 4;                 // elem in [0,1536)
  const int head = e >> 7;
  const size_t r0 = (size_t)tokp * DIMC + e;
  float4 o0 = *(const float4*)(Opart + r0);
  float4 o1 = *(const float4*)(Opart + (size_t)NHT * DIMC + r0);
  const float* ml0 = mlbuf + 2 * ((size_t)tokp * HEADS + head);
  const float* ml1 = mlbuf + 2 * ((size_t)(NHT + tokp) * HEADS + head);
  const float m0 = ml0[0], l0 = ml0[1], m1 = ml1[0], l1 = ml1[1];
  const float mm = fmaxf(m0, m1);
  const float a0 = exp2f(m0 - mm), a1 = exp2f(m1 - mm);
  const float inv = 1.f / (l0 * a0 + l1 * a1);
  uint2 pk;
  pk.x = (unsigned int)f2bf((o0.x * a0 + o1.x * a1) * inv) |
         ((unsigned int)f2bf((o0.y * a0 + o1.y * a1) * inv) << 16);
  pk.y = (unsigned int)f2bf((o0.z * a0 + o1.z * a1) * inv) |
         ((unsigned int)f2bf((o0.w * a0 + o1.w * a1) * inv) << 16);
  *(uint2*)(ab + (size_t)(HTOK + tokp) * DIMC + e) = pk;
}

// ---------------- launch ----------------
extern "C" void kernel_launch(void* const* d_in, const int* in_sizes, int n_in,
                              void* d_out, int out_size, void* d_ws, size_t ws_size,
                              hipStream_t stream)
{
  (void)in_sizes; (void)n_in; (void)out_size; (void)ws_size;
  const float* x     = (const float*)d_in[0];
  const float* freqs = (const float*)d_in[3];
  const float* wq    = (const float*)d_in[4];
  const float* bq    = (const float*)d_in[5];
  const float* wk    = (const float*)d_in[6];
  const float* bk    = (const float*)d_in[7];
  const float* wv    = (const float*)d_in[8];
  const float* bv    = (const float*)d_in[9];
  const float* wo    = (const float*)d_in[10];
  const float* bo    = (const float*)d_in[11];
  const float* nqw   = (const float*)d_in[12];
  const float* nkw   = (const float*)d_in[13];

  char* ws = (char*)d_ws;
  size_t off = 0;
  auto take = [&](size_t bytes) -> void* {
    void* p = ws + off; off += (bytes + 255) & ~(size_t)255; return p;
  };
  // wob first (must survive attention); xb..wvb are dead after QKV GEMM and
  // are overlaid by Opart (23,592,960 B, exact match).
  unsigned short* wob = (unsigned short*)take((size_t)DIMC * DIMC * 2);
  unsigned short* qb  = (unsigned short*)take((size_t)LTOK * DIMC * 2);
  unsigned short* kb  = (unsigned short*)take((size_t)LTOK * DIMC * 2);
  unsigned short* vb  = (unsigned short*)take((size_t)LTOK * DIMC * 2);
  unsigned short* ab  = (unsigned short*)take((size_t)LTOK * DIMC * 2);
  unsigned short* vtb = (unsigned short*)take((size_t)LTOK * DIMC * 2);
  unsigned short* xb  = (unsigned short*)take((size_t)LTOK * DIMC * 2);
  unsigned short* wqb = (unsigned short*)take((size_t)DIMC * DIMC * 2);
  unsigned short* wkb = (unsigned short*)take((size_t)DIMC * DIMC * 2);
  unsigned short* wvb = (unsigned short*)take((size_t)DIMC * DIMC * 2);
  float* mlb = (float*)take((size_t)2 * NHT * HEADS * 2 * sizeof(float));
  float* Opart = (float*)xb;   // overlays xb+wqb+wkb+wvb

  cvt_all_k<<<dim3(13824), dim3(256), 0, stream>>>(x, wq, wk, wv, wo,
                                                   xb, wqb, wkb, wvb, wob);

  gemm_nt<false><<<dim3(DIMC / 128, LTOK / 128, 3), dim3(256), 0, stream>>>(
      xb, wqb, wkb, wvb, bq, bk, bv, qb, kb, vb);

  rms_rope_k<<<dim3(LTOK, 2), dim3(256), 0, stream>>>(qb, kb, nqw, nkw, freqs);
  transpose_v_k<<<dim3(LTOK / 64, DIMC / 64), dim3(256), 0, stream>>>(vb, vtb);

  attn_flash<<<dim3(936), dim3(256), 0, stream>>>(qb, kb, vtb, ab, Opart, mlb);
  merge_k<<<dim3(NHT), dim3(384), 0, stream>>>(Opart, mlb, ab);

  gemm_nt<true><<<dim3(DIMC / 128, LTOK / 128, 1), dim3(256), 0, stream>>>(
      ab, wob, wob, wob, bo, bo, bo, d_out, d_out, d_out);
}